// Round 10
// baseline (569.751 us; speedup 1.0000x reference)
//
#include <hip/hip_runtime.h>
#include <hip/hip_bf16.h>

typedef _Float16 half8 __attribute__((ext_vector_type(8)));
typedef float f32x4 __attribute__((ext_vector_type(4)));
typedef float f32x16 __attribute__((ext_vector_type(16)));

#define B_SZ 64
#define T_SZ 512
#define E_SZ 768
#define H_SZ 256
#define V_SZ 3072

// workspace layout (bytes)
#define WS_X     0u          // _Float16 x[T][B][H]           16,777,216 B
#define WS_WT    16777216u   // _Float16 Wt[256][768] (Wxh^T)    393,216 B
#define WS_WF    17170432u   // _Float16 Wf[65536] Whh 32x32-B   131,072 B
#define WS_H     17301504u   // float    h[64][256]               65,536 B

// fast tanh: 1 - 2/(1+exp(2x)); exact at +/-inf, ~1e-6 rel err
static __device__ __forceinline__ float fast_tanh(float x) {
  float e = __builtin_amdgcn_exp2f(x * 2.8853900817779268f); // exp(2x)
  return 1.0f - 2.0f * __builtin_amdgcn_rcpf(1.0f + e);
}

// ---------------- k0: prep f16 weight layouts (small) ----------------
// Wt[h][e] = Wxh[e][h] (k1 B panels).
// Wf = Whh packed as 32x32x16 MFMA B-fragments:
//   frag(w,nt,kt)[lane][j] = Whh[kt*16 + (lane>>5)*8 + j][w*64 + nt*32 + (lane&31)]
//   flat = (((w*2+nt)*16 + kt)*64 + lane)*8 + j
__global__ __launch_bounds__(256) void k0_convert(
    const float* __restrict__ Wxh,
    const float* __restrict__ Whh,
    _Float16* __restrict__ Wt,
    _Float16* __restrict__ Wf)
{
  int gid = blockIdx.x * 256 + threadIdx.x;           // 768 WGs = 196608
  if (gid < E_SZ * H_SZ) {                            // Wxh[e][h] -> Wt[h][e]
    int e = gid >> 8, h = gid & 255;
    Wt[h * E_SZ + e] = (_Float16)Wxh[gid];
  }
  if (gid < 65536) {
    int j = gid & 7, lane = (gid >> 3) & 63, kt = (gid >> 9) & 15;
    int nt = (gid >> 13) & 1, w = gid >> 14;
    int row = kt * 16 + (lane >> 5) * 8 + j;
    int col = w * 64 + nt * 32 + (lane & 31);
    Wf[gid] = (_Float16)Whh[row * H_SZ + col];
  }
}

// ---------------- k1: x[t,b,:] = emb[idx[b,t],:] @ Wxh  (MFMA f16) ----------------
__global__ __launch_bounds__(256) void k1_xproj(
    const int* __restrict__ idx,
    const float* __restrict__ emb,
    const _Float16* __restrict__ Wt,
    _Float16* __restrict__ x)
{
  const int tid  = threadIdx.x;
  const int w    = tid >> 6;
  const int lane = tid & 63;
  const int m16  = lane & 15;
  const int quad = lane >> 4;
  const int r = blockIdx.x * 64 + w * 16 + m16;     // row in [T*B], r = t*64 + b
  const int t = r >> 6;
  const int b = r & 63;
  const int erow = idx[b * T_SZ + t];
  const float* Arow = emb + (size_t)erow * E_SZ + quad * 8;   // A[m][k=quad*8+j]

  __shared__ __align__(16) _Float16 bp[16 * 64 * 8]; // 16KB fragment-ordered B panel
  int n_[4], kb_[4];
#pragma unroll
  for (int pp = 0; pp < 4; ++pp) {
    int f = tid + 256 * pp;
    n_[pp]  = ((f >> 6) << 4) | (f & 15);
    kb_[pp] = (f >> 4) & 3;
  }
  uint4 stg[4];
#pragma unroll
  for (int pp = 0; pp < 4; ++pp)
    stg[pp] = *(const uint4*)(Wt + (size_t)n_[pp] * E_SZ + kb_[pp] * 8);
  f32x4 af0 = *(const f32x4*)(Arow);
  f32x4 af1 = *(const f32x4*)(Arow + 4);

  f32x4 acc[16];
#pragma unroll
  for (int n = 0; n < 16; ++n) { f32x4 z = {0.f, 0.f, 0.f, 0.f}; acc[n] = z; }

#pragma unroll 1
  for (int ki = 0; ki < 24; ++ki) {
    __syncthreads();
#pragma unroll
    for (int pp = 0; pp < 4; ++pp)
      *(uint4*)(bp + (size_t)(tid + 256 * pp) * 8) = stg[pp];
    __syncthreads();
    if (ki < 23) {
#pragma unroll
      for (int pp = 0; pp < 4; ++pp)
        stg[pp] = *(const uint4*)(Wt + (size_t)n_[pp] * E_SZ + (ki + 1) * 32 + kb_[pp] * 8);
    }
    f32x4 af0n = af0, af1n = af1;
    if (ki < 23) {
      af0n = *(const f32x4*)(Arow + (ki + 1) * 32);
      af1n = *(const f32x4*)(Arow + (ki + 1) * 32 + 4);
    }
    half8 a;
#pragma unroll
    for (int e = 0; e < 4; ++e) { a[e] = (_Float16)af0[e]; a[4 + e] = (_Float16)af1[e]; }
#pragma unroll
    for (int nt = 0; nt < 16; ++nt) {
      half8 bb = *(const half8*)(bp + (size_t)(nt * 64 + lane) * 8);
      acc[nt] = __builtin_amdgcn_mfma_f32_16x16x32_f16(a, bb, acc[nt], 0, 0, 0);
    }
    af0 = af0n; af1 = af1n;
  }
  const int rbase = blockIdx.x * 64 + w * 16 + quad * 4;  // C/D: col=lane&15, row=quad*4+reg
#pragma unroll
  for (int nt = 0; nt < 16; ++nt) {
    const int col = nt * 16 + m16;
#pragma unroll
    for (int rg = 0; rg < 4; ++rg) {
      x[(size_t)(rbase + rg) * H_SZ + col] = (_Float16)acc[nt][rg];
    }
  }
}

// ---------------- k2: recurrence via 32x32x16 MFMA, B parked in a0..a127 ----
// Wave w owns cols [w*64, w*64+64) = 2 N-tiles of 32. B-frag (nt,kt) lives at
// a[(nt*16+kt)*4 .. +3] (r7-proven park). A = h replicated over rows: lane
// reads h[kt*16 + (lane>>5)*8 .. +7] (2 addrs/wave, broadcast). 8 accumulator
// chains (2 nt x 4 K-groups, 4 deep, 8-instr spacing) kill dep latency.
// Issue/step: 32 MFMA x 8 cyc = 256 (vs r7's 512).
#define PARKF(NT, KT, R0, R1, R2, R3) { \
  uint4 q = Wf4[((size_t)((w * 2 + NT) * 16 + KT)) * 64 + lane]; \
  asm volatile("v_accvgpr_write_b32 a" #R0 ", %0" :: "v"(q.x) : "a" #R0); \
  asm volatile("v_accvgpr_write_b32 a" #R1 ", %0" :: "v"(q.y) : "a" #R1); \
  asm volatile("v_accvgpr_write_b32 a" #R2 ", %0" :: "v"(q.z) : "a" #R2); \
  asm volatile("v_accvgpr_write_b32 a" #R3 ", %0" :: "v"(q.w) : "a" #R3); }

__global__
__attribute__((amdgpu_flat_work_group_size(256, 256)))
__attribute__((amdgpu_waves_per_eu(1, 1)))
void k2_rnn(
    const _Float16* __restrict__ Wf,
    const _Float16* __restrict__ x,
    const float* __restrict__ Bh,
    float* __restrict__ hout,
    float* __restrict__ hidout)
{
  const int b    = blockIdx.x;
  const int tid  = threadIdx.x;
  const int w    = tid >> 6;
  const int lane = tid & 63;
  const int l31  = lane & 31;
  const int h5   = lane >> 5;
  __shared__ __align__(16) _Float16 hb[2][H_SZ];
  const uint4* Wf4 = (const uint4*)Wf;

  // park 32 B-fragments: nt0 kt0..15 -> a0..a63, nt1 kt0..15 -> a64..a127
  PARKF(0, 0,  0,  1,  2,  3)  PARKF(0, 1,  4,  5,  6,  7)
  PARKF(0, 2,  8,  9, 10, 11)  PARKF(0, 3, 12, 13, 14, 15)
  PARKF(0, 4, 16, 17, 18, 19)  PARKF(0, 5, 20, 21, 22, 23)
  PARKF(0, 6, 24, 25, 26, 27)  PARKF(0, 7, 28, 29, 30, 31)
  PARKF(0, 8, 32, 33, 34, 35)  PARKF(0, 9, 36, 37, 38, 39)
  PARKF(0,10, 40, 41, 42, 43)  PARKF(0,11, 44, 45, 46, 47)
  PARKF(0,12, 48, 49, 50, 51)  PARKF(0,13, 52, 53, 54, 55)
  PARKF(0,14, 56, 57, 58, 59)  PARKF(0,15, 60, 61, 62, 63)
  PARKF(1, 0, 64, 65, 66, 67)  PARKF(1, 1, 68, 69, 70, 71)
  PARKF(1, 2, 72, 73, 74, 75)  PARKF(1, 3, 76, 77, 78, 79)
  PARKF(1, 4, 80, 81, 82, 83)  PARKF(1, 5, 84, 85, 86, 87)
  PARKF(1, 6, 88, 89, 90, 91)  PARKF(1, 7, 92, 93, 94, 95)
  PARKF(1, 8, 96, 97, 98, 99)  PARKF(1, 9,100,101,102,103)
  PARKF(1,10,104,105,106,107)  PARKF(1,11,108,109,110,111)
  PARKF(1,12,112,113,114,115)  PARKF(1,13,116,117,118,119)
  PARKF(1,14,120,121,122,123)  PARKF(1,15,124,125,126,127)

  const int col0 = w * 64 + l31;
  const int col1 = col0 + 32;
  const float bh0 = Bh[col0];
  const float bh1 = Bh[col1];
  const _Float16* xp0 = x + b * H_SZ + col0;
  const _Float16* xp1 = x + b * H_SZ + col1;
  _Float16 xq0 = xp0[0], xq1 = xp1[0];
  f32x16 zf = {0.f,0.f,0.f,0.f,0.f,0.f,0.f,0.f,0.f,0.f,0.f,0.f,0.f,0.f,0.f,0.f};
  asm volatile("" : "+v"(zf));            // pin zero block (no per-iter remat)
  hb[1][tid] = (_Float16)0.f;             // t=0 reads buffer 1 = zeros
  float h0 = 0.f, h1 = 0.f;
  __syncthreads();

#pragma unroll 1
  for (int t = 0; t < T_SZ; ++t) {
    const int tn = (t < T_SZ - 1) ? (t + 1) : t;
    _Float16 xn0 = xp0[(size_t)tn * (B_SZ * H_SZ)];
    _Float16 xn1 = xp1[(size_t)tn * (B_SZ * H_SZ)];
    const _Float16* hr = hb[(t + 1) & 1];
    // A-frags: lane needs h[kt*16 + h5*8 .. +7]  (row-replicated A)
    half8 v0  = *(const half8*)(hr +   0 + h5 * 8);
    half8 v1  = *(const half8*)(hr +  16 + h5 * 8);
    half8 v2  = *(const half8*)(hr +  32 + h5 * 8);
    half8 v3  = *(const half8*)(hr +  48 + h5 * 8);
    half8 v4  = *(const half8*)(hr +  64 + h5 * 8);
    half8 v5  = *(const half8*)(hr +  80 + h5 * 8);
    half8 v6  = *(const half8*)(hr +  96 + h5 * 8);
    half8 v7  = *(const half8*)(hr + 112 + h5 * 8);
    half8 v8  = *(const half8*)(hr + 128 + h5 * 8);
    half8 v9  = *(const half8*)(hr + 144 + h5 * 8);
    half8 v10 = *(const half8*)(hr + 160 + h5 * 8);
    half8 v11 = *(const half8*)(hr + 176 + h5 * 8);
    half8 v12 = *(const half8*)(hr + 192 + h5 * 8);
    half8 v13 = *(const half8*)(hr + 208 + h5 * 8);
    half8 v14 = *(const half8*)(hr + 224 + h5 * 8);
    half8 v15 = *(const half8*)(hr + 240 + h5 * 8);
    f32x16 c00, c01, c02, c03, c10, c11, c12, c13;
    asm volatile(
      // r=0 (chain heads, srcC = zero)
      "v_mfma_f32_32x32x16_f16 %[c00], %[a0],  a[0:3],    %[z]\n\t"
      "v_mfma_f32_32x32x16_f16 %[c10], %[a0],  a[64:67],  %[z]\n\t"
      "v_mfma_f32_32x32x16_f16 %[c01], %[a4],  a[16:19],  %[z]\n\t"
      "v_mfma_f32_32x32x16_f16 %[c11], %[a4],  a[80:83],  %[z]\n\t"
      "v_mfma_f32_32x32x16_f16 %[c02], %[a8],  a[32:35],  %[z]\n\t"
      "v_mfma_f32_32x32x16_f16 %[c12], %[a8],  a[96:99],  %[z]\n\t"
      "v_mfma_f32_32x32x16_f16 %[c03], %[a12], a[48:51],  %[z]\n\t"
      "v_mfma_f32_32x32x16_f16 %[c13], %[a12], a[112:115],%[z]\n\t"
      // r=1
      "v_mfma_f32_32x32x16_f16 %[c00], %[a1],  a[4:7],    %[c00]\n\t"
      "v_mfma_f32_32x32x16_f16 %[c10], %[a1],  a[68:71],  %[c10]\n\t"
      "v_mfma_f32_32x32x16_f16 %[c01], %[a5],  a[20:23],  %[c01]\n\t"
      "v_mfma_f32_32x32x16_f16 %[c11], %[a5],  a[84:87],  %[c11]\n\t"
      "v_mfma_f32_32x32x16_f16 %[c02], %[a9],  a[36:39],  %[c02]\n\t"
      "v_mfma_f32_32x32x16_f16 %[c12], %[a9],  a[100:103],%[c12]\n\t"
      "v_mfma_f32_32x32x16_f16 %[c03], %[a13], a[52:55],  %[c03]\n\t"
      "v_mfma_f32_32x32x16_f16 %[c13], %[a13], a[116:119],%[c13]\n\t"
      // r=2
      "v_mfma_f32_32x32x16_f16 %[c00], %[a2],  a[8:11],   %[c00]\n\t"
      "v_mfma_f32_32x32x16_f16 %[c10], %[a2],  a[72:75],  %[c10]\n\t"
      "v_mfma_f32_32x32x16_f16 %[c01], %[a6],  a[24:27],  %[c01]\n\t"
      "v_mfma_f32_32x32x16_f16 %[c11], %[a6],  a[88:91],  %[c11]\n\t"
      "v_mfma_f32_32x32x16_f16 %[c02], %[a10], a[40:43],  %[c02]\n\t"
      "v_mfma_f32_32x32x16_f16 %[c12], %[a10], a[104:107],%[c12]\n\t"
      "v_mfma_f32_32x32x16_f16 %[c03], %[a14], a[56:59],  %[c03]\n\t"
      "v_mfma_f32_32x32x16_f16 %[c13], %[a14], a[120:123],%[c13]\n\t"
      // r=3
      "v_mfma_f32_32x32x16_f16 %[c00], %[a3],  a[12:15],  %[c00]\n\t"
      "v_mfma_f32_32x32x16_f16 %[c10], %[a3],  a[76:79],  %[c10]\n\t"
      "v_mfma_f32_32x32x16_f16 %[c01], %[a7],  a[28:31],  %[c01]\n\t"
      "v_mfma_f32_32x32x16_f16 %[c11], %[a7],  a[92:95],  %[c11]\n\t"
      "v_mfma_f32_32x32x16_f16 %[c02], %[a11], a[44:47],  %[c02]\n\t"
      "v_mfma_f32_32x32x16_f16 %[c12], %[a11], a[108:111],%[c12]\n\t"
      "v_mfma_f32_32x32x16_f16 %[c03], %[a15], a[60:63],  %[c03]\n\t"
      "v_mfma_f32_32x32x16_f16 %[c13], %[a15], a[124:127],%[c13]\n\t"
      "s_nop 7\n\t"
      "s_nop 7\n\t"
      "s_nop 7"
      : [c00] "=&v"(c00), [c01] "=&v"(c01), [c02] "=&v"(c02), [c03] "=&v"(c03),
        [c10] "=&v"(c10), [c11] "=&v"(c11), [c12] "=&v"(c12), [c13] "=&v"(c13)
      : [a0] "v"(v0),  [a1] "v"(v1),  [a2] "v"(v2),  [a3] "v"(v3),
        [a4] "v"(v4),  [a5] "v"(v5),  [a6] "v"(v6),  [a7] "v"(v7),
        [a8] "v"(v8),  [a9] "v"(v9),  [a10] "v"(v10), [a11] "v"(v11),
        [a12] "v"(v12), [a13] "v"(v13), [a14] "v"(v14), [a15] "v"(v15),
        [z] "v"(zf));
    // rows replicated -> any reg works; reg 0, col = lane&31 within tile
    float y0 = (c00[0] + c01[0]) + (c02[0] + c03[0]);
    float y1 = (c10[0] + c11[0]) + (c12[0] + c13[0]);
    h0 = fast_tanh(y0 + (float)xq0 + bh0);
    h1 = fast_tanh(y1 + (float)xq1 + bh1);
    if (h5 == 0) {                         // lanes 32..63 are duplicates
      hb[t & 1][col0] = (_Float16)h0;
      hb[t & 1][col1] = (_Float16)h1;
    }
    __syncthreads();
    xq0 = xn0; xq1 = xn1;
  }
  if (h5 == 0) {
    hout[b * H_SZ + col0] = h0;  hout[b * H_SZ + col1] = h1;
    hidout[b * H_SZ + col0] = h0; hidout[b * H_SZ + col1] = h1;
  }
}

// ---------------- k3: out = hidden @ Wy + By  (all f32) ----------------
__global__ __launch_bounds__(256) void k3_out(
    const float* __restrict__ h,
    const float* __restrict__ Wy,
    const float* __restrict__ By,
    float* __restrict__ out)
{
  __shared__ float hs[H_SZ];
  const int c = blockIdx.x;   // vocab chunk
  const int b = blockIdx.y;   // batch
  const int v = c * 256 + threadIdx.x;
  hs[threadIdx.x] = h[b * H_SZ + threadIdx.x];
  __syncthreads();
  float acc = By[v];
#pragma unroll 8
  for (int jj = 0; jj < H_SZ; ++jj) {
    acc += hs[jj] * Wy[(size_t)jj * V_SZ + v];
  }
  out[(size_t)b * V_SZ + v] = acc;
}

extern "C" void kernel_launch(void* const* d_in, const int* in_sizes, int n_in,
                              void* d_out, int out_size, void* d_ws, size_t ws_size,
                              hipStream_t stream)
{
  const int*   idx = (const int*)d_in[0];
  const float* emb = (const float*)d_in[1];
  const float* Wxh = (const float*)d_in[2];
  const float* Whh = (const float*)d_in[3];
  const float* Wy  = (const float*)d_in[4];
  const float* By  = (const float*)d_in[5];
  const float* Bh  = (const float*)d_in[6];

  char* ws = (char*)d_ws;
  _Float16* x    = (_Float16*)(ws + WS_X);
  _Float16* Wt   = (_Float16*)(ws + WS_WT);
  _Float16* Wf   = (_Float16*)(ws + WS_WF);
  float*    hbuf = (float*)(ws + WS_H);

  float* out    = (float*)d_out;
  float* hidout = out + (size_t)B_SZ * V_SZ;

  k0_convert<<<768, 256, 0, stream>>>(Wxh, Whh, Wt, Wf);
  k1_xproj  <<<512, 256, 0, stream>>>(idx, emb, Wt, x);
  k2_rnn    <<<64, 256, 0, stream>>>(Wf, x, Bh, hbuf, hidout);
  k3_out    <<<dim3(12, 64), 256, 0, stream>>>(hbuf, Wy, By, out);
}

// Round 11
// 386.294 us; speedup vs baseline: 1.4749x; 1.4749x over previous
//
#include <hip/hip_runtime.h>
#include <hip/hip_bf16.h>

typedef _Float16 half8 __attribute__((ext_vector_type(8)));
typedef float f32x4 __attribute__((ext_vector_type(4)));

#define B_SZ 64
#define T_SZ 512
#define E_SZ 768
#define H_SZ 256
#define V_SZ 3072

// workspace layout (bytes)
#define WS_X     0u          // _Float16 x[T][B][H]           16,777,216 B
#define WS_WT    16777216u   // _Float16 Wt[256][768] (Wxh^T)    393,216 B
#define WS_WF    17170432u   // _Float16 Wf[65536] Whh MFMA-B    131,072 B
#define WS_H     17301504u   // float    h[64][256]               65,536 B

// fast tanh: 1 - 2/(1+exp(2x)); exact at +/-inf, ~1e-6 rel err
static __device__ __forceinline__ float fast_tanh(float x) {
  float e = __builtin_amdgcn_exp2f(x * 2.8853900817779268f); // exp(2x)
  return 1.0f - 2.0f * __builtin_amdgcn_rcpf(1.0f + e);
}

// ---------------- k0: prep f16 weight layouts (small) ----------------
// Wt[h][e] = Wxh[e][h] (k1 B panels).
// Wf = Whh in 16x16x32 MFMA-B fragment order (r7-validated):
//   frag(nt,kt)[lane][j] = Whh[kt*32 + (lane>>4)*8 + j][nt*16 + (lane&15)]
//   flat = ((nt*8+kt)*64+lane)*8 + j
__global__ __launch_bounds__(256) void k0_convert(
    const float* __restrict__ Wxh,
    const float* __restrict__ Whh,
    _Float16* __restrict__ Wt,
    _Float16* __restrict__ Wf)
{
  int gid = blockIdx.x * 256 + threadIdx.x;           // 768 WGs = 196608
  if (gid < E_SZ * H_SZ) {
    int e = gid >> 8, h = gid & 255;
    Wt[h * E_SZ + e] = (_Float16)Wxh[gid];
  }
  if (gid < 65536) {
    int j = gid & 7, lane = (gid >> 3) & 63, kt = (gid >> 9) & 7, nt = gid >> 12;
    int quad = lane >> 4, n16 = lane & 15;
    int row = kt * 32 + quad * 8 + j, col = nt * 16 + n16;
    Wf[gid] = (_Float16)Whh[row * H_SZ + col];
  }
}

// ---------------- k1: x[t,b,:] = emb[idx[b,t],:] @ Wxh  (MFMA f16) ----------------
// Double-buffered B panel: ONE barrier per ki (was two).
__global__ __launch_bounds__(256) void k1_xproj(
    const int* __restrict__ idx,
    const float* __restrict__ emb,
    const _Float16* __restrict__ Wt,
    _Float16* __restrict__ x)
{
  const int tid  = threadIdx.x;
  const int w    = tid >> 6;
  const int lane = tid & 63;
  const int m16  = lane & 15;
  const int quad = lane >> 4;
  const int r = blockIdx.x * 64 + w * 16 + m16;     // row in [T*B], r = t*64 + b
  const int t = r >> 6;
  const int b = r & 63;
  const int erow = idx[b * T_SZ + t];
  const float* Arow = emb + (size_t)erow * E_SZ + quad * 8;   // A[m][k=quad*8+j]

  __shared__ __align__(16) _Float16 bp[2][16 * 64 * 8]; // 2 x 16KB fragment panels
  int n_[4], kb_[4];
#pragma unroll
  for (int pp = 0; pp < 4; ++pp) {
    int f = tid + 256 * pp;
    n_[pp]  = ((f >> 6) << 4) | (f & 15);
    kb_[pp] = (f >> 4) & 3;
  }
  uint4 stg[4];
#pragma unroll
  for (int pp = 0; pp < 4; ++pp)
    stg[pp] = *(const uint4*)(Wt + (size_t)n_[pp] * E_SZ + kb_[pp] * 8);
  f32x4 af0 = *(const f32x4*)(Arow);
  f32x4 af1 = *(const f32x4*)(Arow + 4);

  f32x4 acc[16];
#pragma unroll
  for (int n = 0; n < 16; ++n) { f32x4 z = {0.f, 0.f, 0.f, 0.f}; acc[n] = z; }

  // stage panel 0
#pragma unroll
  for (int pp = 0; pp < 4; ++pp)
    *(uint4*)(bp[0] + (size_t)(tid + 256 * pp) * 8) = stg[pp];
  __syncthreads();

#pragma unroll 1
  for (int ki = 0; ki < 24; ++ki) {
    const _Float16* cur = bp[ki & 1];
    f32x4 af0n = af0, af1n = af1;
    if (ki < 23) {                            // prefetch next panel + next A
#pragma unroll
      for (int pp = 0; pp < 4; ++pp)
        stg[pp] = *(const uint4*)(Wt + (size_t)n_[pp] * E_SZ + (ki + 1) * 32 + kb_[pp] * 8);
      af0n = *(const f32x4*)(Arow + (ki + 1) * 32);
      af1n = *(const f32x4*)(Arow + (ki + 1) * 32 + 4);
    }
    half8 a;
#pragma unroll
    for (int e = 0; e < 4; ++e) { a[e] = (_Float16)af0[e]; a[4 + e] = (_Float16)af1[e]; }
#pragma unroll
    for (int nt = 0; nt < 16; ++nt) {
      half8 bb = *(const half8*)(cur + (size_t)(nt * 64 + lane) * 8);
      acc[nt] = __builtin_amdgcn_mfma_f32_16x16x32_f16(a, bb, acc[nt], 0, 0, 0);
    }
    if (ki < 23) {                            // write next buffer, one barrier
#pragma unroll
      for (int pp = 0; pp < 4; ++pp)
        *(uint4*)(bp[(ki + 1) & 1] + (size_t)(tid + 256 * pp) * 8) = stg[pp];
      __syncthreads();
    }
    af0 = af0n; af1 = af1n;
  }
  const int rbase = blockIdx.x * 64 + w * 16 + quad * 4;  // C/D: col=lane&15, row=quad*4+reg
#pragma unroll
  for (int nt = 0; nt < 16; ++nt) {
    const int col = nt * 16 + m16;
#pragma unroll
    for (int rg = 0; rg < 4; ++rg) {
      x[(size_t)(rbase + rg) * H_SZ + col] = (_Float16)acc[nt][rg];
    }
  }
}

// ---------------- k2: r7's proven MFMA recurrence, per-K-tile asm split ----
// Wave w owns N-tiles nt=w*4+c; B-frag (c,kt) parked at a[(c*8+kt)*4..+3].
// A = h row-replicated (quad-broadcast ds_read_b128). The 32 MFMAs are split
// into 8 per-kt asm blocks so the compiler emits fine-grained lgkmcnt(N) —
// block 0 waits only on read 0; reads 1..7 finish under MFMA execution
// (r7's single block forced lgkmcnt(0) = ~200 cyc serialization).
#define LDFRAG(C, KT, R0, R1, R2, R3) { \
  uint4 q = Wf4[(((size_t)(w * 4 + C) * 8 + KT) * 64) + lane]; \
  asm volatile("v_accvgpr_write_b32 a" #R0 ", %0" :: "v"(q.x) : "a" #R0); \
  asm volatile("v_accvgpr_write_b32 a" #R1 ", %0" :: "v"(q.y) : "a" #R1); \
  asm volatile("v_accvgpr_write_b32 a" #R2 ", %0" :: "v"(q.z) : "a" #R2); \
  asm volatile("v_accvgpr_write_b32 a" #R3 ", %0" :: "v"(q.w) : "a" #R3); }

// kt=0: fresh accumulators from pinned zero
#define MFMA_K0(A0, Z) \
  asm volatile( \
    "v_mfma_f32_16x16x32_f16 %[t0], %[a], a[0:3],   %[z]\n\t" \
    "v_mfma_f32_16x16x32_f16 %[t1], %[a], a[32:35], %[z]\n\t" \
    "v_mfma_f32_16x16x32_f16 %[t2], %[a], a[64:67], %[z]\n\t" \
    "v_mfma_f32_16x16x32_f16 %[t3], %[a], a[96:99], %[z]" \
    : [t0] "=&v"(acc0), [t1] "=&v"(acc1), [t2] "=&v"(acc2), [t3] "=&v"(acc3) \
    : [a] "v"(A0), [z] "v"(Z));

#define MFMA_KT(A0, B0, B1, B2, B3) \
  asm volatile( \
    "v_mfma_f32_16x16x32_f16 %[t0], %[a], a[" #B0 "], %[t0]\n\t" \
    "v_mfma_f32_16x16x32_f16 %[t1], %[a], a[" #B1 "], %[t1]\n\t" \
    "v_mfma_f32_16x16x32_f16 %[t2], %[a], a[" #B2 "], %[t2]\n\t" \
    "v_mfma_f32_16x16x32_f16 %[t3], %[a], a[" #B3 "], %[t3]" \
    : [t0] "+v"(acc0), [t1] "+v"(acc1), [t2] "+v"(acc2), [t3] "+v"(acc3) \
    : [a] "v"(A0));

#define MFMA_K7(A0, B0, B1, B2, B3) \
  asm volatile( \
    "v_mfma_f32_16x16x32_f16 %[t0], %[a], a[" #B0 "], %[t0]\n\t" \
    "v_mfma_f32_16x16x32_f16 %[t1], %[a], a[" #B1 "], %[t1]\n\t" \
    "v_mfma_f32_16x16x32_f16 %[t2], %[a], a[" #B2 "], %[t2]\n\t" \
    "v_mfma_f32_16x16x32_f16 %[t3], %[a], a[" #B3 "], %[t3]\n\t" \
    "s_nop 7\n\t" \
    "s_nop 7" \
    : [t0] "+v"(acc0), [t1] "+v"(acc1), [t2] "+v"(acc2), [t3] "+v"(acc3) \
    : [a] "v"(A0));

__global__ __launch_bounds__(256) void k2_rnn(
    const _Float16* __restrict__ Wf,
    const _Float16* __restrict__ x,
    const float* __restrict__ Bh,
    float* __restrict__ hout,
    float* __restrict__ hidout)
{
  const int b    = blockIdx.x;
  const int tid  = threadIdx.x;
  const int w    = tid >> 6;
  const int lane = tid & 63;
  const int quad = lane >> 4;
  __shared__ __align__(16) _Float16 hb[2][H_SZ];   // h as f16, double-buffered
  const uint4* Wf4 = (const uint4*)Wf;

  LDFRAG(0,0,  0,  1,  2,  3)  LDFRAG(0,1,  4,  5,  6,  7)
  LDFRAG(0,2,  8,  9, 10, 11)  LDFRAG(0,3, 12, 13, 14, 15)
  LDFRAG(0,4, 16, 17, 18, 19)  LDFRAG(0,5, 20, 21, 22, 23)
  LDFRAG(0,6, 24, 25, 26, 27)  LDFRAG(0,7, 28, 29, 30, 31)
  LDFRAG(1,0, 32, 33, 34, 35)  LDFRAG(1,1, 36, 37, 38, 39)
  LDFRAG(1,2, 40, 41, 42, 43)  LDFRAG(1,3, 44, 45, 46, 47)
  LDFRAG(1,4, 48, 49, 50, 51)  LDFRAG(1,5, 52, 53, 54, 55)
  LDFRAG(1,6, 56, 57, 58, 59)  LDFRAG(1,7, 60, 61, 62, 63)
  LDFRAG(2,0, 64, 65, 66, 67)  LDFRAG(2,1, 68, 69, 70, 71)
  LDFRAG(2,2, 72, 73, 74, 75)  LDFRAG(2,3, 76, 77, 78, 79)
  LDFRAG(2,4, 80, 81, 82, 83)  LDFRAG(2,5, 84, 85, 86, 87)
  LDFRAG(2,6, 88, 89, 90, 91)  LDFRAG(2,7, 92, 93, 94, 95)
  LDFRAG(3,0, 96, 97, 98, 99)  LDFRAG(3,1,100,101,102,103)
  LDFRAG(3,2,104,105,106,107)  LDFRAG(3,3,108,109,110,111)
  LDFRAG(3,4,112,113,114,115)  LDFRAG(3,5,116,117,118,119)
  LDFRAG(3,6,120,121,122,123)  LDFRAG(3,7,124,125,126,127)

  const float bhj = Bh[tid];
  const _Float16* xp = x + b * H_SZ + tid;
  _Float16 xq = xp[0];
  f32x4 zero4 = {0.f, 0.f, 0.f, 0.f};
  asm volatile("" : "+v"(zero4));        // pin: no remat-mov adjacent to MFMA srcC
  hb[1][tid] = (_Float16)0.f;            // t=0 reads buffer 1 = zeros
  float hval = 0.f;
  __syncthreads();

#pragma unroll 1
  for (int t = 0; t < T_SZ; ++t) {
    const int tn = (t < T_SZ - 1) ? (t + 1) : t;
    _Float16 xn = xp[(size_t)tn * (B_SZ * H_SZ)];   // prefetch next x
    const _Float16* hr = hb[(t + 1) & 1];
    // A fragments: h[kt*32+quad*8 .. +7], same for all 16 rows (quad-broadcast)
    half8 va0 = *(const half8*)(hr +   0 + quad * 8);
    half8 va1 = *(const half8*)(hr +  32 + quad * 8);
    half8 va2 = *(const half8*)(hr +  64 + quad * 8);
    half8 va3 = *(const half8*)(hr +  96 + quad * 8);
    half8 va4 = *(const half8*)(hr + 128 + quad * 8);
    half8 va5 = *(const half8*)(hr + 160 + quad * 8);
    half8 va6 = *(const half8*)(hr + 192 + quad * 8);
    half8 va7 = *(const half8*)(hr + 224 + quad * 8);
    f32x4 acc0, acc1, acc2, acc3;
    MFMA_K0(va0, zero4)
    MFMA_KT(va1,   4:7,  36:39,  68:71, 100:103)
    MFMA_KT(va2,  8:11,  40:43,  72:75, 104:107)
    MFMA_KT(va3, 12:15,  44:47,  76:79, 108:111)
    MFMA_KT(va4, 16:19,  48:51,  80:83, 112:115)
    MFMA_KT(va5, 20:23,  52:55,  84:87, 116:119)
    MFMA_KT(va6, 24:27,  56:59,  88:91, 120:123)
    MFMA_K7(va7, 28:31,  60:63,  92:95, 124:127)
    // D rows identical (A rows replicated); lane (quad q, n16) takes tile q:
    float v0 = acc0[0], v1 = acc1[0], v2 = acc2[0], v3 = acc3[0];
    float ylo = (quad & 1) ? v1 : v0;
    float yhi = (quad & 1) ? v3 : v2;
    float y   = (quad & 2) ? yhi : ylo;     // y = (h @ Whh)[tid]
    hval = fast_tanh(y + (float)xq + bhj);
    hb[t & 1][tid] = (_Float16)hval;
    __syncthreads();
    xq = xn;
  }
  hout[b * H_SZ + tid] = hval;
  hidout[b * H_SZ + tid] = hval;
}

// ---------------- k3: out = hidden @ Wy + By  (all f32) ----------------
__global__ __launch_bounds__(256) void k3_out(
    const float* __restrict__ h,
    const float* __restrict__ Wy,
    const float* __restrict__ By,
    float* __restrict__ out)
{
  __shared__ float hs[H_SZ];
  const int c = blockIdx.x;   // vocab chunk
  const int b = blockIdx.y;   // batch
  const int v = c * 256 + threadIdx.x;
  hs[threadIdx.x] = h[b * H_SZ + threadIdx.x];
  __syncthreads();
  float acc = By[v];
#pragma unroll 8
  for (int jj = 0; jj < H_SZ; ++jj) {
    acc += hs[jj] * Wy[(size_t)jj * V_SZ + v];
  }
  out[(size_t)b * V_SZ + v] = acc;
}

extern "C" void kernel_launch(void* const* d_in, const int* in_sizes, int n_in,
                              void* d_out, int out_size, void* d_ws, size_t ws_size,
                              hipStream_t stream)
{
  const int*   idx = (const int*)d_in[0];
  const float* emb = (const float*)d_in[1];
  const float* Wxh = (const float*)d_in[2];
  const float* Whh = (const float*)d_in[3];
  const float* Wy  = (const float*)d_in[4];
  const float* By  = (const float*)d_in[5];
  const float* Bh  = (const float*)d_in[6];

  char* ws = (char*)d_ws;
  _Float16* x    = (_Float16*)(ws + WS_X);
  _Float16* Wt   = (_Float16*)(ws + WS_WT);
  _Float16* Wf   = (_Float16*)(ws + WS_WF);
  float*    hbuf = (float*)(ws + WS_H);

  float* out    = (float*)d_out;
  float* hidout = out + (size_t)B_SZ * V_SZ;

  k0_convert<<<768, 256, 0, stream>>>(Wxh, Whh, Wt, Wf);
  k1_xproj  <<<512, 256, 0, stream>>>(idx, emb, Wt, x);
  k2_rnn    <<<64, 256, 0, stream>>>(Wf, x, Bh, hbuf, hidout);
  k3_out    <<<dim3(12, 64), 256, 0, stream>>>(hbuf, Wy, By, out);
}